// Round 8
// baseline (418.960 us; speedup 1.0000x reference)
//
#include <hip/hip_runtime.h>

// ---------------- Problem constants ----------------
#define BATCH   2
#define SEQLEN  1024
#define DMODEL  1024
#define DINNER  2048
#define DSTATE  16
#define DCONV   4
#define DTRANK  64
#define GDIM    96              // DTRANK + 2*DSTATE
#define MROWS   (BATCH*SEQLEN)  // 2048

#define NCHUNK  16              // chunks over L
#define LCHUNK  64              // SEQLEN / NCHUNK

typedef __attribute__((ext_vector_type(8))) short bf16x8_t;
typedef __attribute__((ext_vector_type(4))) float f32x4_t;
typedef unsigned short ushort_t;

// bf16 <-> f32 helpers (round-to-nearest-even)
__device__ __forceinline__ unsigned short f2bf(float x) {
    union { float f; unsigned int u; } v; v.f = x;
    unsigned int r = v.u + 0x7FFFu + ((v.u >> 16) & 1u);
    return (unsigned short)(r >> 16);
}
__device__ __forceinline__ float bf2f(unsigned short h) {
    union { unsigned int u; float f; } v; v.u = ((unsigned int)h) << 16;
    return v.f;
}
__device__ __forceinline__ void split8(const float* x, bf16x8_t& hi, bf16x8_t& lo) {
    #pragma unroll
    for (int j = 0; j < 8; j++) {
        unsigned short h = f2bf(x[j]);
        float r = x[j] - bf2f(h);
        hi[j] = (short)h;
        lo[j] = (short)f2bf(r);
    }
}

// ---------------- weight pre-split: f32 -> hi/lo bf16 ----------------
__global__ void split_kernel(const float* __restrict__ src,
                             ushort_t* __restrict__ hi, ushort_t* __restrict__ lo, int n) {
    int i = blockIdx.x * 256 + threadIdx.x;
    if (i >= n) return;
    float v = src[i];
    unsigned short h = f2bf(v);
    hi[i] = h;
    lo[i] = f2bf(v - bf2f(h));
}

// ---------------- 128x128 split-precision NT MFMA GEMM ----------------
// C[m,n] = sum_k A[m,k]*W[n,k]. hi/lo bf16 operands, 3 MFMAs (hh+hl+lh) ~2^-18 rel err.
// ASPLIT: 1 = A is f32 (split in staging), 0 = A pre-split hi/lo
// WSPLIT: 1 = W is f32 (split in staging), 0 = W pre-split hi/lo
// EPI: 0 = f32 partial store to out0 + blockIdx.z*M*N  (split-K)
//      1 = f32 softplus(v + bias[n]) -> out0
//      3 = xz split: col < DINNER -> out0 f32; else out1 f32 (both stride DINNER)
// M%128==0; K/gridDim.z % 32 == 0; N ragged allowed.
template<int ASPLIT, int WSPLIT, int EPI>
__global__ __launch_bounds__(256)
void gemm128(const float* __restrict__ Af,
             const ushort_t* __restrict__ Ahi, const ushort_t* __restrict__ Alo,
             const float* __restrict__ Wf,
             const ushort_t* __restrict__ Whi, const ushort_t* __restrict__ Wlo,
             float* __restrict__ out0, float* __restrict__ out1,
             const float* __restrict__ bias, int M, int N, int K) {
    __shared__ __align__(16) short As[2][128][40];   // [hi/lo][row][k], pad 32->40
    __shared__ __align__(16) short Bs[2][128][40];

    const int tid  = threadIdx.x;
    const int m0   = blockIdx.x * 128;
    const int n0   = blockIdx.y * 128;
    const int klen = K / gridDim.z;
    const int kbeg = blockIdx.z * klen;

    const int srow = tid >> 1;          // 0..127 staging row
    const int sseg = (tid & 1) * 16;    // 0 or 16 (shorts)
    const int w    = tid >> 6;          // wave 0..3
    const int lane = tid & 63;
    const int quad = lane >> 4;
    const int l15  = lane & 15;
    const int wm   = (w >> 1) * 64;
    const int wn   = (w & 1) * 64;

    f32x4_t acc[4][4];
    #pragma unroll
    for (int i = 0; i < 4; i++)
        #pragma unroll
        for (int j = 0; j < 4; j++)
            acc[i][j] = (f32x4_t){0.f, 0.f, 0.f, 0.f};

    const int arow = m0 + srow;
    const int brow = n0 + srow;
    const bool bval = (brow < N);

    for (int k0 = 0; k0 < klen; k0 += 32) {
        const int kk = kbeg + k0 + sseg;
        bf16x8_t ah0, ah1, al0, al1;
        if (ASPLIT) {
            float ax[16];
            const float* p = Af + (size_t)arow * K + kk;
            *(float4*)(ax)      = *(const float4*)(p);
            *(float4*)(ax + 4)  = *(const float4*)(p + 4);
            *(float4*)(ax + 8)  = *(const float4*)(p + 8);
            *(float4*)(ax + 12) = *(const float4*)(p + 12);
            split8(ax, ah0, al0);
            split8(ax + 8, ah1, al1);
        } else {
            size_t o = (size_t)arow * K + kk;
            ah0 = *(const bf16x8_t*)(Ahi + o);
            ah1 = *(const bf16x8_t*)(Ahi + o + 8);
            al0 = *(const bf16x8_t*)(Alo + o);
            al1 = *(const bf16x8_t*)(Alo + o + 8);
        }
        bf16x8_t bh0, bh1, bl0, bl1;
        if (WSPLIT) {
            float wx[16];
            #pragma unroll
            for (int j = 0; j < 16; j++) wx[j] = 0.f;
            if (bval) {
                const float* p = Wf + (size_t)brow * K + kk;
                *(float4*)(wx)      = *(const float4*)(p);
                *(float4*)(wx + 4)  = *(const float4*)(p + 4);
                *(float4*)(wx + 8)  = *(const float4*)(p + 8);
                *(float4*)(wx + 12) = *(const float4*)(p + 12);
            }
            split8(wx, bh0, bl0);
            split8(wx + 8, bh1, bl1);
        } else {
            if (bval) {
                size_t o = (size_t)brow * K + kk;
                bh0 = *(const bf16x8_t*)(Whi + o);
                bh1 = *(const bf16x8_t*)(Whi + o + 8);
                bl0 = *(const bf16x8_t*)(Wlo + o);
                bl1 = *(const bf16x8_t*)(Wlo + o + 8);
            } else {
                #pragma unroll
                for (int j = 0; j < 8; j++) { bh0[j] = 0; bh1[j] = 0; bl0[j] = 0; bl1[j] = 0; }
            }
        }

        __syncthreads();   // previous iteration's readers done
        *(bf16x8_t*)(&As[0][srow][sseg])     = ah0;
        *(bf16x8_t*)(&As[0][srow][sseg + 8]) = ah1;
        *(bf16x8_t*)(&As[1][srow][sseg])     = al0;
        *(bf16x8_t*)(&As[1][srow][sseg + 8]) = al1;
        *(bf16x8_t*)(&Bs[0][srow][sseg])     = bh0;
        *(bf16x8_t*)(&Bs[0][srow][sseg + 8]) = bh1;
        *(bf16x8_t*)(&Bs[1][srow][sseg])     = bl0;
        *(bf16x8_t*)(&Bs[1][srow][sseg + 8]) = bl1;
        __syncthreads();

        bf16x8_t afh[4], afl[4], bfh[4], bfl[4];
        #pragma unroll
        for (int mi = 0; mi < 4; mi++) {
            afh[mi] = *(const bf16x8_t*)(&As[0][wm + mi * 16 + l15][quad * 8]);
            afl[mi] = *(const bf16x8_t*)(&As[1][wm + mi * 16 + l15][quad * 8]);
        }
        #pragma unroll
        for (int ni = 0; ni < 4; ni++) {
            bfh[ni] = *(const bf16x8_t*)(&Bs[0][wn + ni * 16 + l15][quad * 8]);
            bfl[ni] = *(const bf16x8_t*)(&Bs[1][wn + ni * 16 + l15][quad * 8]);
        }
        #pragma unroll
        for (int mi = 0; mi < 4; mi++)
            #pragma unroll
            for (int ni = 0; ni < 4; ni++) {
                acc[mi][ni] = __builtin_amdgcn_mfma_f32_16x16x32_bf16(afh[mi], bfh[ni], acc[mi][ni], 0, 0, 0);
                acc[mi][ni] = __builtin_amdgcn_mfma_f32_16x16x32_bf16(afh[mi], bfl[ni], acc[mi][ni], 0, 0, 0);
                acc[mi][ni] = __builtin_amdgcn_mfma_f32_16x16x32_bf16(afl[mi], bfh[ni], acc[mi][ni], 0, 0, 0);
            }
    }

    const size_t zoff = (size_t)blockIdx.z * M * N;
    #pragma unroll
    for (int mi = 0; mi < 4; mi++) {
        #pragma unroll
        for (int ni = 0; ni < 4; ni++) {
            #pragma unroll
            for (int r = 0; r < 4; r++) {
                int gm = m0 + wm + mi * 16 + quad * 4 + r;
                int gn = n0 + wn + ni * 16 + l15;
                if (gn < N) {
                    float v = acc[mi][ni][r];
                    if (EPI == 0) {
                        out0[zoff + (size_t)gm * N + gn] = v;
                    } else if (EPI == 1) {
                        float t = v + bias[gn];
                        out0[(size_t)gm * N + gn] = (t > 20.f) ? t : log1pf(__expf(t));
                    } else {
                        if (gn < DINNER)
                            out0[(size_t)gm * DINNER + gn] = v;
                        else
                            out1[(size_t)gm * DINNER + (gn - DINNER)] = v;
                    }
                }
            }
        }
    }
}

// ---------------- causal depthwise conv (k=4) + bias + SiLU -> xc hi/lo ----------------
__global__ __launch_bounds__(256)
void conv_silu_kernel(const float* __restrict__ x,
                      const float* __restrict__ cw,
                      const float* __restrict__ cb,
                      ushort_t* __restrict__ xc_hi,
                      ushort_t* __restrict__ xc_lo) {
    int idx = blockIdx.x * 256 + threadIdx.x;   // MROWS*DINNER
    int d  = idx & (DINNER - 1);
    int bl = idx >> 11;
    int l  = bl & (SEQLEN - 1);
    float acc = cb[d];
    #pragma unroll
    for (int j = 0; j < DCONV; j++) {
        int lj = l - (DCONV - 1) + j;
        if (lj >= 0)
            acc += cw[d * DCONV + j] * x[(size_t)(bl - (DCONV - 1) + j) * DINNER + d];
    }
    float v = acc / (1.f + __expf(-acc));   // silu
    unsigned short h = f2bf(v);
    xc_hi[idx] = h;
    xc_lo[idx] = f2bf(v - bf2f(h));
}

// ---------------- text gate ----------------
__global__ void gate_kernel(const float* __restrict__ x_text,
                            const float* __restrict__ gw,
                            const float* __restrict__ gb,
                            float* __restrict__ gate) {
    int blk = blockIdx.x;        // BATCH*GDIM blocks of 64
    int b = blk / GDIM, j = blk % GDIM;
    int lane = threadIdx.x;
    float s = 0.f;
    for (int k = lane; k < DMODEL; k += 64)
        s += x_text[b * DMODEL + k] * gw[j * DMODEL + k];
    #pragma unroll
    for (int off = 32; off > 0; off >>= 1) s += __shfl_down(s, off);
    if (lane == 0) {
        float t = s + gb[j];
        gate[b * GDIM + j] = 1.f / (1.f + __expf(-t));
    }
}

// ---------------- reduce split-K partials + gate; split into dt hi/lo, B, C ----------------
__global__ void gatemul_kernel(const float* __restrict__ xp,   // [8][MROWS][GDIM]
                               const float* __restrict__ gate,
                               ushort_t* __restrict__ dt_hi,
                               ushort_t* __restrict__ dt_lo,
                               float* __restrict__ Bm,
                               float* __restrict__ Cm) {
    int idx = blockIdx.x * 256 + threadIdx.x;   // MROWS*GDIM
    if (idx >= MROWS * GDIM) return;
    int j  = idx % GDIM;
    int bl = idx / GDIM;
    int b  = bl >> 10;
    float v = 0.f;
    #pragma unroll
    for (int z = 0; z < 8; z++)
        v += xp[(size_t)z * MROWS * GDIM + idx];
    v *= gate[b * GDIM + j];
    if (j < DTRANK) {
        unsigned short h = f2bf(v);
        dt_hi[bl * DTRANK + j] = h;
        dt_lo[bl * DTRANK + j] = f2bf(v - bf2f(h));
    } else if (j < DTRANK + DSTATE) {
        Bm[bl * DSTATE + (j - DTRANK)] = v;
    } else {
        Cm[bl * DSTATE + (j - DTRANK - DSTATE)] = v;
    }
}

// ---------------- scan pass 1: per-chunk local h and dA-product ----------------
__global__ __launch_bounds__(256)
void scan1_kernel(const float* __restrict__ delta,
                  const ushort_t* __restrict__ xc_hi,
                  const ushort_t* __restrict__ xc_lo,
                  const float* __restrict__ Bm,
                  const float* __restrict__ A_log,
                  float* __restrict__ hfin,
                  float* __restrict__ aprod) {
    __shared__ float sBm[LCHUNK][DSTATE];
    int tid = threadIdx.x;
    int d = blockIdx.x * 256 + tid;
    int b = blockIdx.y;
    int c = blockIdx.z;
    int l0 = c * LCHUNK;
    for (int t = tid; t < LCHUNK * DSTATE; t += 256)
        sBm[t >> 4][t & 15] = Bm[((size_t)(b * SEQLEN + l0 + (t >> 4))) * DSTATE + (t & 15)];
    __syncthreads();

    float Ac[DSTATE];
    #pragma unroll
    for (int n = 0; n < DSTATE; n++)
        Ac[n] = -__expf(A_log[d * DSTATE + n]);
    float h[DSTATE], p[DSTATE];
    #pragma unroll
    for (int n = 0; n < DSTATE; n++) { h[n] = 0.f; p[n] = 1.f; }

    for (int s = 0; s < LCHUNK; s++) {
        size_t ix = (size_t)(b * SEQLEN + l0 + s) * DINNER + d;
        float dv = delta[ix];
        float xv = bf2f(xc_hi[ix]) + bf2f(xc_lo[ix]);
        float dx = dv * xv;
        #pragma unroll
        for (int n = 0; n < DSTATE; n++) {
            float e = __expf(dv * Ac[n]);
            h[n] = h[n] * e + dx * sBm[s][n];
            p[n] *= e;
        }
    }
    size_t base = ((size_t)(b * DINNER + d) * NCHUNK + c) * DSTATE;
    #pragma unroll
    for (int n = 0; n < DSTATE; n++) { hfin[base + n] = h[n]; aprod[base + n] = p[n]; }
}

// ---------------- scan pass 2: chunk-level prefix (h_start in place) ----------------
__global__ void scan2_kernel(float* __restrict__ hfin,
                             const float* __restrict__ aprod) {
    int idx = blockIdx.x * 256 + threadIdx.x;   // BATCH*DINNER*DSTATE
    int n  = idx & 15;
    int bd = idx >> 4;
    size_t base = (size_t)bd * NCHUNK * DSTATE + n;
    float hs = 0.f;
    for (int c = 0; c < NCHUNK; c++) {
        size_t o = base + (size_t)c * DSTATE;
        float hf = hfin[o];
        float ap = aprod[o];
        hfin[o] = hs;            // h_start for chunk c
        hs = hf + ap * hs;
    }
}

// ---------------- scan pass 3: replay with h0, emit y hi/lo (in place over xc) ----------------
__global__ __launch_bounds__(256)
void scan3_kernel(const float* __restrict__ delta,
                  ushort_t* __restrict__ xc_hi,   // in: xc, out: y
                  ushort_t* __restrict__ xc_lo,
                  const float* __restrict__ z,
                  const float* __restrict__ Bm,
                  const float* __restrict__ Cm,
                  const float* __restrict__ A_log,
                  const float* __restrict__ Dp,
                  const float* __restrict__ hstart) {
    __shared__ float sBm[LCHUNK][DSTATE];
    __shared__ float sCm[LCHUNK][DSTATE];
    int tid = threadIdx.x;
    int d = blockIdx.x * 256 + tid;
    int b = blockIdx.y;
    int c = blockIdx.z;
    int l0 = c * LCHUNK;
    for (int t = tid; t < LCHUNK * DSTATE; t += 256) {
        size_t src = ((size_t)(b * SEQLEN + l0 + (t >> 4))) * DSTATE + (t & 15);
        sBm[t >> 4][t & 15] = Bm[src];
        sCm[t >> 4][t & 15] = Cm[src];
    }
    __syncthreads();

    float Ac[DSTATE];
    #pragma unroll
    for (int n = 0; n < DSTATE; n++)
        Ac[n] = -__expf(A_log[d * DSTATE + n]);
    float h[DSTATE];
    size_t base = ((size_t)(b * DINNER + d) * NCHUNK + c) * DSTATE;
    #pragma unroll
    for (int n = 0; n < DSTATE; n++) h[n] = hstart[base + n];
    float Dv = Dp[d];

    for (int s = 0; s < LCHUNK; s++) {
        size_t ix = (size_t)(b * SEQLEN + l0 + s) * DINNER + d;
        float dv = delta[ix];
        float xv = bf2f(xc_hi[ix]) + bf2f(xc_lo[ix]);
        float dx = dv * xv;
        float y = 0.f;
        #pragma unroll
        for (int n = 0; n < DSTATE; n++) {
            float e = __expf(dv * Ac[n]);
            h[n] = h[n] * e + dx * sBm[s][n];
            y += h[n] * sCm[s][n];
        }
        float zv = z[ix];
        float o = (y + Dv * xv) * (zv / (1.f + __expf(-zv)));
        unsigned short hh = f2bf(o);
        xc_hi[ix] = hh;                   // same thread read-then-write: safe in place
        xc_lo[ix] = f2bf(o - bf2f(hh));
    }
}

// ---------------- out_proj split-K reduce ----------------
__global__ void reduce2_kernel(const float* __restrict__ p, float* __restrict__ out, int n) {
    int i = blockIdx.x * 256 + threadIdx.x;
    if (i < n) out[i] = p[i] + p[(size_t)n + i];
}

// ---------------- launch ----------------
extern "C" void kernel_launch(void* const* d_in, const int* in_sizes, int n_in,
                              void* d_out, int out_size, void* d_ws, size_t ws_size,
                              hipStream_t stream) {
    const float* hidden   = (const float*)d_in[0];
    const float* x_text   = (const float*)d_in[1];
    const float* in_proj  = (const float*)d_in[2];
    const float* conv_w   = (const float*)d_in[3];
    const float* conv_b   = (const float*)d_in[4];
    const float* x_proj   = (const float*)d_in[5];
    const float* dt_proj  = (const float*)d_in[6];
    const float* dt_bias  = (const float*)d_in[7];
    const float* A_log    = (const float*)d_in[8];
    const float* Dparam   = (const float*)d_in[9];
    const float* out_proj = (const float*)d_in[10];
    const float* gate_w   = (const float*)d_in[11];
    const float* gate_b   = (const float*)d_in[12];

    char* ws = (char*)d_ws;
    size_t off = 0;
    auto alloc = [&](size_t bytes) -> char* {
        char* p = ws + off;
        off += (bytes + 255) & ~(size_t)255;
        return p;
    };
    // ~69.5 MB total with aliasing
    float*    xbuf   = (float*)alloc((size_t)MROWS * DINNER * 4);   // x; later delta; later out_proj partials (2x8.39MB)
    float*    zbuf   = (float*)alloc((size_t)MROWS * DINNER * 4);   // z
    ushort_t* w_in_h = (ushort_t*)alloc((size_t)2 * DINNER * DMODEL * 2);  // 8.39 MB  (region reused: xdbl_p, hfin/aprod)
    ushort_t* w_in_l = (ushort_t*)alloc((size_t)2 * DINNER * DMODEL * 2);  // 8.39 MB
    ushort_t* w_x_h  = (ushort_t*)alloc((size_t)GDIM * DINNER * 2);
    ushort_t* w_x_l  = (ushort_t*)alloc((size_t)GDIM * DINNER * 2);
    ushort_t* w_dt_h = (ushort_t*)alloc((size_t)DINNER * DTRANK * 2);
    ushort_t* w_dt_l = (ushort_t*)alloc((size_t)DINNER * DTRANK * 2);
    ushort_t* xc_h   = (ushort_t*)alloc((size_t)MROWS * DINNER * 2);  // 8.39 MB; later y_hi in place
    ushort_t* xc_l   = (ushort_t*)alloc((size_t)MROWS * DINNER * 2);  // 8.39 MB; later y_lo
    float*    gate   = (float*)alloc((size_t)BATCH * GDIM * 4);
    float*    Bm     = (float*)alloc((size_t)MROWS * DSTATE * 4);
    float*    Cm     = (float*)alloc((size_t)MROWS * DSTATE * 4);
    ushort_t* dt_h   = (ushort_t*)alloc((size_t)MROWS * DTRANK * 2);
    ushort_t* dt_l   = (ushort_t*)alloc((size_t)MROWS * DTRANK * 2);

    // aliases (lifetimes disjoint):
    float* delta  = xbuf;                        // live [dt_proj .. scan3]; x dead after conv
    float* outp   = xbuf;                        // live [out_proj .. reduce]; delta dead after scan3 (16.78 MB = 2 partials)
    float* xdbl_p = (float*)w_in_h;              // 6.29 MB, live [x_proj .. gatemul]; w_in dead after in_proj
    float* hfin   = (float*)w_in_h;              // 4.19 MB, live [scan1 .. scan3]; xdbl_p dead after gatemul
    float* aprod  = (float*)(w_in_h + (size_t)DINNER * DINNER);  // next 4.19 MB (within w_in_h's 8.39 MB)

    // 0. pre-split weights into hi/lo bf16
    split_kernel<<<(2 * DINNER * DMODEL + 255) / 256, 256, 0, stream>>>(in_proj, w_in_h, w_in_l, 2 * DINNER * DMODEL);
    split_kernel<<<(GDIM * DINNER + 255) / 256, 256, 0, stream>>>(x_proj, w_x_h, w_x_l, GDIM * DINNER);
    split_kernel<<<(DINNER * DTRANK + 255) / 256, 256, 0, stream>>>(dt_proj, w_dt_h, w_dt_l, DINNER * DTRANK);

    // 1. in_proj: xz = hidden @ in_proj^T  (2048 x 4096, K=1024) -> x / z
    gemm128<1, 0, 3><<<dim3(MROWS / 128, (2 * DINNER) / 128, 1), 256, 0, stream>>>(
        hidden, nullptr, nullptr, nullptr, w_in_h, w_in_l, xbuf, zbuf, nullptr,
        MROWS, 2 * DINNER, DMODEL);

    // 2. causal conv + silu -> xc hi/lo
    conv_silu_kernel<<<(MROWS * DINNER) / 256, 256, 0, stream>>>(xbuf, conv_w, conv_b, xc_h, xc_l);

    // 3. text gate
    gate_kernel<<<BATCH * GDIM, 64, 0, stream>>>(x_text, gate_w, gate_b, gate);

    // 4. x_proj: x_dbl = xc @ x_proj^T  (2048 x 96, K=2048), split-K=8 -> partials
    gemm128<0, 0, 0><<<dim3(MROWS / 128, 1, 8), 256, 0, stream>>>(
        nullptr, xc_h, xc_l, nullptr, w_x_h, w_x_l, xdbl_p, nullptr, nullptr,
        MROWS, GDIM, DINNER);

    // 5. reduce partials + gate -> dt hi/lo, Bm, Cm
    gatemul_kernel<<<(MROWS * GDIM + 255) / 256, 256, 0, stream>>>(
        xdbl_p, gate, dt_h, dt_l, Bm, Cm);

    // 6. dt_proj + softplus: delta  (2048 x 2048, K=64) -> f32 over dead x
    gemm128<0, 0, 1><<<dim3(MROWS / 128, DINNER / 128, 1), 256, 0, stream>>>(
        nullptr, dt_h, dt_l, nullptr, w_dt_h, w_dt_l, delta, nullptr, dt_bias,
        MROWS, DINNER, DTRANK);

    // 7-9. chunked parallel scan; scan3 writes y hi/lo in place over xc
    scan1_kernel<<<dim3(DINNER / 256, BATCH, NCHUNK), 256, 0, stream>>>(
        delta, xc_h, xc_l, Bm, A_log, hfin, aprod);
    scan2_kernel<<<(BATCH * DINNER * DSTATE) / 256, 256, 0, stream>>>(hfin, aprod);
    scan3_kernel<<<dim3(DINNER / 256, BATCH, NCHUNK), 256, 0, stream>>>(
        delta, xc_h, xc_l, zbuf, Bm, Cm, A_log, Dparam, hfin);

    // 10. out_proj (2048 x 1024, K=2048), split-K=2, W split in staging -> partials over dead delta
    gemm128<0, 1, 0><<<dim3(MROWS / 128, DMODEL / 128, 2), 256, 0, stream>>>(
        nullptr, xc_h, xc_l, out_proj, nullptr, nullptr, outp, nullptr, nullptr,
        MROWS, DMODEL, DINNER);

    // 11. reduce partials -> d_out f32
    reduce2_kernel<<<(MROWS * DMODEL + 255) / 256, 256, 0, stream>>>(
        outp, (float*)d_out, MROWS * DMODEL);
}

// Round 9
// 367.260 us; speedup vs baseline: 1.1408x; 1.1408x over previous
//
#include <hip/hip_runtime.h>

// ---------------- Problem constants ----------------
#define BATCH   2
#define SEQLEN  1024
#define DMODEL  1024
#define DINNER  2048
#define DSTATE  16
#define DCONV   4
#define DTRANK  64
#define GDIM    96              // DTRANK + 2*DSTATE
#define MROWS   (BATCH*SEQLEN)  // 2048

#define NCHUNK  16              // chunks over L
#define LCHUNK  64              // SEQLEN / NCHUNK

typedef __attribute__((ext_vector_type(8))) short bf16x8_t;
typedef __attribute__((ext_vector_type(4))) float f32x4_t;
typedef unsigned short ushort_t;

// bf16 <-> f32 helpers (round-to-nearest-even)
__device__ __forceinline__ unsigned short f2bf(float x) {
    union { float f; unsigned int u; } v; v.f = x;
    unsigned int r = v.u + 0x7FFFu + ((v.u >> 16) & 1u);
    return (unsigned short)(r >> 16);
}
__device__ __forceinline__ float bf2f(unsigned short h) {
    union { unsigned int u; float f; } v; v.u = ((unsigned int)h) << 16;
    return v.f;
}

// ---------------- fused pre-split of all GEMM operands: f32 -> hi/lo bf16 ----------------
#define N1 (MROWS*DMODEL)        // hidden      2,097,152
#define N2 (2*DINNER*DMODEL)     // in_proj_w   8,388,608
#define N3 (GDIM*DINNER)         // x_proj_w      196,608
#define N4 (DINNER*DTRANK)       // dt_proj_w     131,072
#define N5 (DMODEL*DINNER)       // out_proj_w  2,097,152
__global__ __launch_bounds__(256)
void split5_kernel(const float* __restrict__ s1, const float* __restrict__ s2,
                   const float* __restrict__ s3, const float* __restrict__ s4,
                   const float* __restrict__ s5,
                   ushort_t* h1h, ushort_t* h1l, ushort_t* h2h, ushort_t* h2l,
                   ushort_t* h3h, ushort_t* h3l, ushort_t* h4h, ushort_t* h4l,
                   ushort_t* h5h, ushort_t* h5l) {
    int idx = blockIdx.x * 256 + threadIdx.x;
    const float* src; ushort_t *oh, *ol;
    if (idx < N1)                 { src = s1; oh = h1h; ol = h1l; }
    else if ((idx -= N1) < N2)    { src = s2; oh = h2h; ol = h2l; }
    else if ((idx -= N2) < N3)    { src = s3; oh = h3h; ol = h3l; }
    else if ((idx -= N3) < N4)    { src = s4; oh = h4h; ol = h4l; }
    else if ((idx -= N4) < N5)    { src = s5; oh = h5h; ol = h5l; }
    else return;
    float v = src[idx];
    unsigned short h = f2bf(v);
    oh[idx] = h;
    ol[idx] = f2bf(v - bf2f(h));
}

// ---------------- 128x64 split-precision NT MFMA GEMM ----------------
// C[m,n] = sum_k A[m,k]*W[n,k]. All operands pre-split hi/lo bf16; 3 MFMAs
// (hh+hl+lh) ~2^-18 rel err. M%128==0; K/gridDim.z % 32 == 0; N ragged ok.
// EPI: 0 = f32 partial -> out0 + blockIdx.z*M*N   (split-K)
//      1 = f32 softplus(v + bias[n]) -> out0
//      3 = xz split: col < DINNER -> out0; else out1 (both stride DINNER)
template<int EPI>
__global__ __launch_bounds__(256)
void gemm64(const ushort_t* __restrict__ Ahi, const ushort_t* __restrict__ Alo,
            const ushort_t* __restrict__ Whi, const ushort_t* __restrict__ Wlo,
            float* __restrict__ out0, float* __restrict__ out1,
            const float* __restrict__ bias, int M, int N, int K) {
    __shared__ __align__(16) short As[2][128][40];   // 20 KB
    __shared__ __align__(16) short Bs[2][64][40];    // 10 KB

    const int tid  = threadIdx.x;
    const int m0   = blockIdx.x * 128;
    const int n0   = blockIdx.y * 64;
    const int klen = K / gridDim.z;
    const int kbeg = blockIdx.z * klen;

    const int srow = tid >> 1;          // 0..127
    const int sseg = (tid & 1) * 16;    // 0 or 16 shorts
    const int w    = tid >> 6;          // wave 0..3
    const int lane = tid & 63;
    const int quad = lane >> 4;
    const int l15  = lane & 15;
    const int wm   = (w >> 1) * 64;
    const int wn   = (w & 1) * 32;

    f32x4_t acc[4][2];
    #pragma unroll
    for (int i = 0; i < 4; i++)
        #pragma unroll
        for (int j = 0; j < 2; j++)
            acc[i][j] = (f32x4_t){0.f, 0.f, 0.f, 0.f};

    const int arow = m0 + srow;
    const bool bact = (tid < 128);
    const int brow = n0 + srow;          // only meaningful when bact
    const bool bval = bact && (brow < N);

    for (int k0 = 0; k0 < klen; k0 += 32) {
        const int kk = kbeg + k0 + sseg;
        size_t ao = (size_t)arow * K + kk;
        bf16x8_t a0h = *(const bf16x8_t*)(Ahi + ao);
        bf16x8_t a1h = *(const bf16x8_t*)(Ahi + ao + 8);
        bf16x8_t a0l = *(const bf16x8_t*)(Alo + ao);
        bf16x8_t a1l = *(const bf16x8_t*)(Alo + ao + 8);

        bf16x8_t b0h, b1h, b0l, b1l;
        if (bval) {
            size_t bo = (size_t)brow * K + kk;
            b0h = *(const bf16x8_t*)(Whi + bo);
            b1h = *(const bf16x8_t*)(Whi + bo + 8);
            b0l = *(const bf16x8_t*)(Wlo + bo);
            b1l = *(const bf16x8_t*)(Wlo + bo + 8);
        } else {
            #pragma unroll
            for (int j = 0; j < 8; j++) { b0h[j] = 0; b1h[j] = 0; b0l[j] = 0; b1l[j] = 0; }
        }

        __syncthreads();   // previous iteration's readers done
        *(bf16x8_t*)(&As[0][srow][sseg])     = a0h;
        *(bf16x8_t*)(&As[0][srow][sseg + 8]) = a1h;
        *(bf16x8_t*)(&As[1][srow][sseg])     = a0l;
        *(bf16x8_t*)(&As[1][srow][sseg + 8]) = a1l;
        if (bact) {
            *(bf16x8_t*)(&Bs[0][srow][sseg])     = b0h;
            *(bf16x8_t*)(&Bs[0][srow][sseg + 8]) = b1h;
            *(bf16x8_t*)(&Bs[1][srow][sseg])     = b0l;
            *(bf16x8_t*)(&Bs[1][srow][sseg + 8]) = b1l;
        }
        __syncthreads();

        bf16x8_t afh[4], afl[4], bfh[2], bfl[2];
        #pragma unroll
        for (int mi = 0; mi < 4; mi++) {
            afh[mi] = *(const bf16x8_t*)(&As[0][wm + mi * 16 + l15][quad * 8]);
            afl[mi] = *(const bf16x8_t*)(&As[1][wm + mi * 16 + l15][quad * 8]);
        }
        #pragma unroll
        for (int ni = 0; ni < 2; ni++) {
            bfh[ni] = *(const bf16x8_t*)(&Bs[0][wn + ni * 16 + l15][quad * 8]);
            bfl[ni] = *(const bf16x8_t*)(&Bs[1][wn + ni * 16 + l15][quad * 8]);
        }
        #pragma unroll
        for (int mi = 0; mi < 4; mi++)
            #pragma unroll
            for (int ni = 0; ni < 2; ni++) {
                acc[mi][ni] = __builtin_amdgcn_mfma_f32_16x16x32_bf16(afh[mi], bfh[ni], acc[mi][ni], 0, 0, 0);
                acc[mi][ni] = __builtin_amdgcn_mfma_f32_16x16x32_bf16(afh[mi], bfl[ni], acc[mi][ni], 0, 0, 0);
                acc[mi][ni] = __builtin_amdgcn_mfma_f32_16x16x32_bf16(afl[mi], bfh[ni], acc[mi][ni], 0, 0, 0);
            }
    }

    const size_t zoff = (size_t)blockIdx.z * M * N;
    #pragma unroll
    for (int mi = 0; mi < 4; mi++) {
        #pragma unroll
        for (int ni = 0; ni < 2; ni++) {
            #pragma unroll
            for (int r = 0; r < 4; r++) {
                int gm = m0 + wm + mi * 16 + quad * 4 + r;
                int gn = n0 + wn + ni * 16 + l15;
                if (gn < N) {
                    float v = acc[mi][ni][r];
                    if (EPI == 0) {
                        out0[zoff + (size_t)gm * N + gn] = v;
                    } else if (EPI == 1) {
                        float t = v + bias[gn];
                        out0[(size_t)gm * N + gn] = (t > 20.f) ? t : log1pf(__expf(t));
                    } else {
                        if (gn < DINNER)
                            out0[(size_t)gm * DINNER + gn] = v;
                        else
                            out1[(size_t)gm * DINNER + (gn - DINNER)] = v;
                    }
                }
            }
        }
    }
}

// ---------------- fused: causal conv+silu (blocks [0,16384)) + text gate (blocks after) ----------------
#define CONVBLK ((MROWS*DINNER)/256)   // 16384
__global__ __launch_bounds__(256)
void convgate_kernel(const float* __restrict__ x,
                     const float* __restrict__ cw,
                     const float* __restrict__ cb,
                     ushort_t* __restrict__ xc_hi,
                     ushort_t* __restrict__ xc_lo,
                     const float* __restrict__ xt,
                     const float* __restrict__ gw,
                     const float* __restrict__ gb,
                     float* __restrict__ gate) {
    if (blockIdx.x < CONVBLK) {
        int idx = blockIdx.x * 256 + threadIdx.x;
        int d  = idx & (DINNER - 1);
        int bl = idx >> 11;
        int l  = bl & (SEQLEN - 1);
        float acc = cb[d];
        #pragma unroll
        for (int j = 0; j < DCONV; j++) {
            int lj = l - (DCONV - 1) + j;
            if (lj >= 0)
                acc += cw[d * DCONV + j] * x[(size_t)(bl - (DCONV - 1) + j) * DINNER + d];
        }
        float v = acc / (1.f + __expf(-acc));   // silu
        unsigned short h = f2bf(v);
        xc_hi[idx] = h;
        xc_lo[idx] = f2bf(v - bf2f(h));
    } else {
        int g = blockIdx.x - CONVBLK;        // 0..BATCH*GDIM-1
        int b = g / GDIM, j = g % GDIM;
        int tid = threadIdx.x;
        float s = 0.f;
        for (int k = tid; k < DMODEL; k += 256)
            s += xt[b * DMODEL + k] * gw[j * DMODEL + k];
        #pragma unroll
        for (int o = 32; o > 0; o >>= 1) s += __shfl_down(s, o);
        __shared__ float red[4];
        if ((tid & 63) == 0) red[tid >> 6] = s;
        __syncthreads();
        if (tid == 0) {
            float t = red[0] + red[1] + red[2] + red[3] + gb[j];
            gate[b * GDIM + j] = 1.f / (1.f + __expf(-t));
        }
    }
}

// ---------------- reduce split-K partials + gate; split into dt hi/lo, B, C ----------------
__global__ void gatemul_kernel(const float* __restrict__ xp,   // [8][MROWS][GDIM]
                               const float* __restrict__ gate,
                               ushort_t* __restrict__ dt_hi,
                               ushort_t* __restrict__ dt_lo,
                               float* __restrict__ Bm,
                               float* __restrict__ Cm) {
    int idx = blockIdx.x * 256 + threadIdx.x;
    if (idx >= MROWS * GDIM) return;
    int j  = idx % GDIM;
    int bl = idx / GDIM;
    int b  = bl >> 10;
    float v = 0.f;
    #pragma unroll
    for (int z = 0; z < 8; z++)
        v += xp[(size_t)z * MROWS * GDIM + idx];
    v *= gate[b * GDIM + j];
    if (j < DTRANK) {
        unsigned short h = f2bf(v);
        dt_hi[bl * DTRANK + j] = h;
        dt_lo[bl * DTRANK + j] = f2bf(v - bf2f(h));
    } else if (j < DTRANK + DSTATE) {
        Bm[bl * DSTATE + (j - DTRANK)] = v;
    } else {
        Cm[bl * DSTATE + (j - DTRANK - DSTATE)] = v;
    }
}

// ---------------- scan pass 1: per-chunk local h and dA-product ----------------
__global__ __launch_bounds__(256)
void scan1_kernel(const float* __restrict__ delta,
                  const ushort_t* __restrict__ xc_hi,
                  const ushort_t* __restrict__ xc_lo,
                  const float* __restrict__ Bm,
                  const float* __restrict__ A_log,
                  float* __restrict__ hfin,
                  float* __restrict__ aprod) {
    __shared__ float sBm[LCHUNK][DSTATE];
    int tid = threadIdx.x;
    int d = blockIdx.x * 256 + tid;
    int b = blockIdx.y;
    int c = blockIdx.z;
    int l0 = c * LCHUNK;
    for (int t = tid; t < LCHUNK * DSTATE; t += 256)
        sBm[t >> 4][t & 15] = Bm[((size_t)(b * SEQLEN + l0 + (t >> 4))) * DSTATE + (t & 15)];
    __syncthreads();

    float Ac[DSTATE];
    #pragma unroll
    for (int n = 0; n < DSTATE; n++)
        Ac[n] = -__expf(A_log[d * DSTATE + n]);
    float h[DSTATE], p[DSTATE];
    #pragma unroll
    for (int n = 0; n < DSTATE; n++) { h[n] = 0.f; p[n] = 1.f; }

    for (int s = 0; s < LCHUNK; s++) {
        size_t ix = (size_t)(b * SEQLEN + l0 + s) * DINNER + d;
        float dv = delta[ix];
        float xv = bf2f(xc_hi[ix]) + bf2f(xc_lo[ix]);
        float dx = dv * xv;
        #pragma unroll
        for (int n = 0; n < DSTATE; n++) {
            float e = __expf(dv * Ac[n]);
            h[n] = h[n] * e + dx * sBm[s][n];
            p[n] *= e;
        }
    }
    size_t base = ((size_t)(b * DINNER + d) * NCHUNK + c) * DSTATE;
    #pragma unroll
    for (int n = 0; n < DSTATE; n++) { hfin[base + n] = h[n]; aprod[base + n] = p[n]; }
}

// ---------------- scan pass 3: self-prefix + replay, emit y hi/lo in place over xc ----------------
__global__ __launch_bounds__(256)
void scan3_kernel(const float* __restrict__ delta,
                  ushort_t* __restrict__ xc_hi,   // in: xc, out: y
                  ushort_t* __restrict__ xc_lo,
                  const float* __restrict__ z,
                  const float* __restrict__ Bm,
                  const float* __restrict__ Cm,
                  const float* __restrict__ A_log,
                  const float* __restrict__ Dp,
                  const float* __restrict__ hfin,
                  const float* __restrict__ aprod) {
    __shared__ float sBm[LCHUNK][DSTATE];
    __shared__ float sCm[LCHUNK][DSTATE];
    int tid = threadIdx.x;
    int d = blockIdx.x * 256 + tid;
    int b = blockIdx.y;
    int c = blockIdx.z;
    int l0 = c * LCHUNK;
    for (int t = tid; t < LCHUNK * DSTATE; t += 256) {
        size_t src = ((size_t)(b * SEQLEN + l0 + (t >> 4))) * DSTATE + (t & 15);
        sBm[t >> 4][t & 15] = Bm[src];
        sCm[t >> 4][t & 15] = Cm[src];
    }
    __syncthreads();

    float Ac[DSTATE];
    #pragma unroll
    for (int n = 0; n < DSTATE; n++)
        Ac[n] = -__expf(A_log[d * DSTATE + n]);

    // self-prefix over chunks 0..c-1 (replaces the old scan2 dispatch)
    float h[DSTATE];
    #pragma unroll
    for (int n = 0; n < DSTATE; n++) h[n] = 0.f;
    size_t cb = ((size_t)(b * DINNER + d) * NCHUNK) * DSTATE;
    for (int cc = 0; cc < c; cc++) {
        size_t o = cb + (size_t)cc * DSTATE;
        #pragma unroll
        for (int n = 0; n < DSTATE; n++)
            h[n] = hfin[o + n] + aprod[o + n] * h[n];
    }
    float Dv = Dp[d];

    for (int s = 0; s < LCHUNK; s++) {
        size_t ix = (size_t)(b * SEQLEN + l0 + s) * DINNER + d;
        float dv = delta[ix];
        float xv = bf2f(xc_hi[ix]) + bf2f(xc_lo[ix]);
        float dx = dv * xv;
        float y = 0.f;
        #pragma unroll
        for (int n = 0; n < DSTATE; n++) {
            float e = __expf(dv * Ac[n]);
            h[n] = h[n] * e + dx * sBm[s][n];
            y += h[n] * sCm[s][n];
        }
        float zv = z[ix];
        float o = (y + Dv * xv) * (zv / (1.f + __expf(-zv)));
        unsigned short hh = f2bf(o);
        xc_hi[ix] = hh;                   // same thread read-then-write: safe in place
        xc_lo[ix] = f2bf(o - bf2f(hh));
    }
}

// ---------------- out_proj split-K reduce ----------------
__global__ void reduce2_kernel(const float* __restrict__ p, float* __restrict__ out, int n) {
    int i = blockIdx.x * 256 + threadIdx.x;
    if (i < n) out[i] = p[i] + p[(size_t)n + i];
}

// ---------------- launch ----------------
extern "C" void kernel_launch(void* const* d_in, const int* in_sizes, int n_in,
                              void* d_out, int out_size, void* d_ws, size_t ws_size,
                              hipStream_t stream) {
    const float* hidden   = (const float*)d_in[0];
    const float* x_text   = (const float*)d_in[1];
    const float* in_proj  = (const float*)d_in[2];
    const float* conv_w   = (const float*)d_in[3];
    const float* conv_b   = (const float*)d_in[4];
    const float* x_proj   = (const float*)d_in[5];
    const float* dt_proj  = (const float*)d_in[6];
    const float* dt_bias  = (const float*)d_in[7];
    const float* A_log    = (const float*)d_in[8];
    const float* Dparam   = (const float*)d_in[9];
    const float* out_proj = (const float*)d_in[10];
    const float* gate_w   = (const float*)d_in[11];
    const float* gate_b   = (const float*)d_in[12];

    char* ws = (char*)d_ws;
    size_t off = 0;
    auto alloc = [&](size_t bytes) -> char* {
        char* p = ws + off;
        off += (bytes + 255) & ~(size_t)255;
        return p;
    };
    // ~78 MB total with lifetime-disjoint aliasing
    ushort_t* h_hi   = (ushort_t*)alloc((size_t)N1 * 2);   // 4.19 MB
    ushort_t* h_lo   = (ushort_t*)alloc((size_t)N1 * 2);
    ushort_t* w_in_h = (ushort_t*)alloc((size_t)N2 * 2);   // 8.39 MB -> xc_h/y_h after in_proj
    ushort_t* w_in_l = (ushort_t*)alloc((size_t)N2 * 2);   // 8.39 MB -> xc_l/y_l
    ushort_t* w_x_h  = (ushort_t*)alloc((size_t)N3 * 2);
    ushort_t* w_x_l  = (ushort_t*)alloc((size_t)N3 * 2);
    ushort_t* w_dt_h = (ushort_t*)alloc((size_t)N4 * 2);
    ushort_t* w_dt_l = (ushort_t*)alloc((size_t)N4 * 2);
    ushort_t* w_o_h  = (ushort_t*)alloc((size_t)N5 * 2);   // 4.19 MB
    ushort_t* w_o_l  = (ushort_t*)alloc((size_t)N5 * 2);
    float*    X      = (float*)alloc((size_t)MROWS * DINNER * 4);  // 16.78 MB: x -> xdbl_p -> delta -> outp
    float*    zbuf   = (float*)alloc((size_t)MROWS * DINNER * 4);  // 16.78 MB
    float*    hfin   = (float*)alloc((size_t)BATCH * DINNER * NCHUNK * DSTATE * 4);  // 4.19 MB
    float*    aprod  = (float*)alloc((size_t)BATCH * DINNER * NCHUNK * DSTATE * 4);  // 4.19 MB
    float*    gate   = (float*)alloc((size_t)BATCH * GDIM * 4);
    float*    Bm     = (float*)alloc((size_t)MROWS * DSTATE * 4);
    float*    Cm     = (float*)alloc((size_t)MROWS * DSTATE * 4);
    ushort_t* dt_h   = (ushort_t*)alloc((size_t)MROWS * DTRANK * 2);
    ushort_t* dt_l   = (ushort_t*)alloc((size_t)MROWS * DTRANK * 2);

    // aliases (lifetimes disjoint, all ordered by the stream):
    ushort_t* xc_h   = w_in_h;     // live after in_proj consumed w_in
    ushort_t* xc_l   = w_in_l;
    float*    xdbl_p = X;          // 6.3 MB, live [x_proj..gatemul]; x dead after conv
    float*    delta  = X;          // live [dt_proj..scan3]
    float*    outp   = X;          // 16.78 MB (2 partials), live [out_proj..reduce2]

    // 1. pre-split all GEMM operands (hidden + 4 weight matrices) in ONE dispatch
    split5_kernel<<<(N1 + N2 + N3 + N4 + N5 + 255) / 256, 256, 0, stream>>>(
        hidden, in_proj, x_proj, dt_proj, out_proj,
        h_hi, h_lo, w_in_h, w_in_l, w_x_h, w_x_l, w_dt_h, w_dt_l, w_o_h, w_o_l);

    // 2. in_proj: xz = hidden @ in_proj^T  (2048 x 4096, K=1024) -> x f32 (X) / z f32
    gemm64<3><<<dim3(MROWS / 128, (2 * DINNER) / 64, 1), 256, 0, stream>>>(
        h_hi, h_lo, w_in_h, w_in_l, X, zbuf, nullptr, MROWS, 2 * DINNER, DMODEL);

    // 3. conv+silu -> xc hi/lo (over dead w_in)  ++  text gate (fused dispatch)
    convgate_kernel<<<CONVBLK + BATCH * GDIM, 256, 0, stream>>>(
        X, conv_w, conv_b, xc_h, xc_l, x_text, gate_w, gate_b, gate);

    // 4. x_proj: x_dbl = xc @ x_proj^T  (2048 x 96, K=2048), split-K=8 -> partials (X, x dead)
    gemm64<0><<<dim3(MROWS / 128, 2, 8), 256, 0, stream>>>(
        xc_h, xc_l, w_x_h, w_x_l, xdbl_p, nullptr, nullptr, MROWS, GDIM, DINNER);

    // 5. reduce partials + gate -> dt hi/lo, Bm, Cm
    gatemul_kernel<<<(MROWS * GDIM + 255) / 256, 256, 0, stream>>>(
        xdbl_p, gate, dt_h, dt_l, Bm, Cm);

    // 6. dt_proj + softplus: delta  (2048 x 2048, K=64) -> f32 (X, xdbl dead)
    gemm64<1><<<dim3(MROWS / 128, DINNER / 64, 1), 256, 0, stream>>>(
        dt_h, dt_l, w_dt_h, w_dt_l, delta, nullptr, dt_bias, MROWS, DINNER, DTRANK);

    // 7-8. chunked parallel scan (scan2 folded into scan3's self-prefix)
    scan1_kernel<<<dim3(DINNER / 256, BATCH, NCHUNK), 256, 0, stream>>>(
        delta, xc_h, xc_l, Bm, A_log, hfin, aprod);
    scan3_kernel<<<dim3(DINNER / 256, BATCH, NCHUNK), 256, 0, stream>>>(
        delta, xc_h, xc_l, zbuf, Bm, Cm, A_log, Dparam, hfin, aprod);

    // 9. out_proj (2048 x 1024, K=2048), split-K=2 -> partials (X, delta dead)
    gemm64<0><<<dim3(MROWS / 128, DMODEL / 64, 2), 256, 0, stream>>>(
        xc_h, xc_l, w_o_h, w_o_l, outp, nullptr, nullptr, MROWS, DMODEL, DINNER);

    // 10. reduce partials -> d_out f32
    reduce2_kernel<<<(MROWS * DMODEL + 255) / 256, 256, 0, stream>>>(
        outp, (float*)d_out, MROWS * DMODEL);
}

// Round 10
// 326.531 us; speedup vs baseline: 1.2831x; 1.1247x over previous
//
#include <hip/hip_runtime.h>

// ---------------- Problem constants ----------------
#define BATCH   2
#define SEQLEN  1024
#define DMODEL  1024
#define DINNER  2048
#define DSTATE  16
#define DCONV   4
#define DTRANK  64
#define GDIM    96              // DTRANK + 2*DSTATE
#define MROWS   (BATCH*SEQLEN)  // 2048

#define NCHUNK  16              // chunks over L
#define LCHUNK  64              // SEQLEN / NCHUNK

typedef __attribute__((ext_vector_type(8))) short bf16x8_t;
typedef __attribute__((ext_vector_type(4))) float f32x4_t;
typedef unsigned short ushort_t;

// bf16 <-> f32 helpers (round-to-nearest-even)
__device__ __forceinline__ unsigned short f2bf(float x) {
    union { float f; unsigned int u; } v; v.f = x;
    unsigned int r = v.u + 0x7FFFu + ((v.u >> 16) & 1u);
    return (unsigned short)(r >> 16);
}
__device__ __forceinline__ float bf2f(unsigned short h) {
    union { unsigned int u; float f; } v; v.u = ((unsigned int)h) << 16;
    return v.f;
}

// ---------------- fused f32 -> bf16 convert of all GEMM operands ----------------
#define N1 (MROWS*DMODEL)        // hidden
#define N2 (2*DINNER*DMODEL)     // in_proj_w
#define N3 (GDIM*DINNER)         // x_proj_w
#define N4 (DINNER*DTRANK)       // dt_proj_w
#define N5 (DMODEL*DINNER)       // out_proj_w
__global__ __launch_bounds__(256)
void cvt5_kernel(const float* __restrict__ s1, const float* __restrict__ s2,
                 const float* __restrict__ s3, const float* __restrict__ s4,
                 const float* __restrict__ s5,
                 ushort_t* o1, ushort_t* o2, ushort_t* o3, ushort_t* o4, ushort_t* o5) {
    int idx = blockIdx.x * 256 + threadIdx.x;
    const float* src; ushort_t* dst;
    if (idx < N1)              { src = s1; dst = o1; }
    else if ((idx -= N1) < N2) { src = s2; dst = o2; }
    else if ((idx -= N2) < N3) { src = s3; dst = o3; }
    else if ((idx -= N3) < N4) { src = s4; dst = o4; }
    else if ((idx -= N4) < N5) { src = s5; dst = o5; }
    else return;
    dst[idx] = f2bf(src[idx]);
}

// ---------------- 128x128 bf16 NT MFMA GEMM (f32 accumulate) ----------------
// C[m,n] = sum_k A[m,k]*W[n,k]. A,W bf16 row-major. M%128==0; K/gridDim.z%32==0;
// N ragged allowed. 4 waves, each computing 64x64 (4x4 of 16x16x32).
// EPI: 0 = f32 partial -> out0 + blockIdx.z*M*N  (split-K)
//      1 = bf16 softplus(v + bias[n]) -> out0
//      3 = xz split: col < DINNER -> f32 out0; else f32 out1 (both stride DINNER)
template<int EPI>
__global__ __launch_bounds__(256)
void gemm_bf(const ushort_t* __restrict__ A, const ushort_t* __restrict__ W,
             void* __restrict__ out0, void* __restrict__ out1,
             const float* __restrict__ bias, int M, int N, int K) {
    __shared__ __align__(16) short As[128][40];   // 10 KB, pad 32->40
    __shared__ __align__(16) short Bs[128][40];   // 10 KB

    const int tid  = threadIdx.x;
    const int m0   = blockIdx.x * 128;
    const int n0   = blockIdx.y * 128;
    const int klen = K / gridDim.z;
    const int kbeg = blockIdx.z * klen;

    const int srow = tid >> 1;          // 0..127 staging row
    const int sseg = (tid & 1) * 16;    // 0 or 16 shorts
    const int w    = tid >> 6;          // wave 0..3
    const int lane = tid & 63;
    const int quad = lane >> 4;
    const int l15  = lane & 15;
    const int wm   = (w >> 1) * 64;
    const int wn   = (w & 1) * 64;

    f32x4_t acc[4][4];
    #pragma unroll
    for (int i = 0; i < 4; i++)
        #pragma unroll
        for (int j = 0; j < 4; j++)
            acc[i][j] = (f32x4_t){0.f, 0.f, 0.f, 0.f};

    const int arow = m0 + srow;
    const int brow = n0 + srow;
    const bool bval = (brow < N);

    for (int k0 = 0; k0 < klen; k0 += 32) {
        const int kk = kbeg + k0 + sseg;
        size_t ao = (size_t)arow * K + kk;
        bf16x8_t a0 = *(const bf16x8_t*)(A + ao);
        bf16x8_t a1 = *(const bf16x8_t*)(A + ao + 8);
        bf16x8_t b0, b1;
        if (bval) {
            size_t bo = (size_t)brow * K + kk;
            b0 = *(const bf16x8_t*)(W + bo);
            b1 = *(const bf16x8_t*)(W + bo + 8);
        } else {
            #pragma unroll
            for (int j = 0; j < 8; j++) { b0[j] = 0; b1[j] = 0; }
        }

        __syncthreads();   // previous iteration's readers done
        *(bf16x8_t*)(&As[srow][sseg])     = a0;
        *(bf16x8_t*)(&As[srow][sseg + 8]) = a1;
        *(bf16x8_t*)(&Bs[srow][sseg])     = b0;
        *(bf16x8_t*)(&Bs[srow][sseg + 8]) = b1;
        __syncthreads();

        bf16x8_t af[4], bf[4];
        #pragma unroll
        for (int mi = 0; mi < 4; mi++)
            af[mi] = *(const bf16x8_t*)(&As[wm + mi * 16 + l15][quad * 8]);
        #pragma unroll
        for (int ni = 0; ni < 4; ni++)
            bf[ni] = *(const bf16x8_t*)(&Bs[wn + ni * 16 + l15][quad * 8]);
        #pragma unroll
        for (int mi = 0; mi < 4; mi++)
            #pragma unroll
            for (int ni = 0; ni < 4; ni++)
                acc[mi][ni] = __builtin_amdgcn_mfma_f32_16x16x32_bf16(af[mi], bf[ni], acc[mi][ni], 0, 0, 0);
    }

    const size_t zoff = (size_t)blockIdx.z * M * N;
    #pragma unroll
    for (int mi = 0; mi < 4; mi++) {
        #pragma unroll
        for (int ni = 0; ni < 4; ni++) {
            #pragma unroll
            for (int r = 0; r < 4; r++) {
                int gm = m0 + wm + mi * 16 + quad * 4 + r;
                int gn = n0 + wn + ni * 16 + l15;
                if (gn < N) {
                    float v = acc[mi][ni][r];
                    if (EPI == 0) {
                        ((float*)out0)[zoff + (size_t)gm * N + gn] = v;
                    } else if (EPI == 1) {
                        float t = v + bias[gn];
                        float sp = (t > 20.f) ? t : log1pf(__expf(t));
                        ((ushort_t*)out0)[(size_t)gm * N + gn] = f2bf(sp);
                    } else {
                        if (gn < DINNER)
                            ((float*)out0)[(size_t)gm * DINNER + gn] = v;
                        else
                            ((float*)out1)[(size_t)gm * DINNER + (gn - DINNER)] = v;
                    }
                }
            }
        }
    }
}

// ---------------- fused: causal conv+silu (blocks [0,CONVBLK)) + text gate ----------------
#define CONVBLK ((MROWS*DINNER)/256)   // 16384
__global__ __launch_bounds__(256)
void convgate_kernel(const float* __restrict__ x,
                     const float* __restrict__ cw,
                     const float* __restrict__ cb,
                     ushort_t* __restrict__ xc,
                     const float* __restrict__ xt,
                     const float* __restrict__ gw,
                     const float* __restrict__ gb,
                     float* __restrict__ gate) {
    if (blockIdx.x < CONVBLK) {
        int idx = blockIdx.x * 256 + threadIdx.x;
        int d  = idx & (DINNER - 1);
        int bl = idx >> 11;
        int l  = bl & (SEQLEN - 1);
        float acc = cb[d];
        #pragma unroll
        for (int j = 0; j < DCONV; j++) {
            int lj = l - (DCONV - 1) + j;
            if (lj >= 0)
                acc += cw[d * DCONV + j] * x[(size_t)(bl - (DCONV - 1) + j) * DINNER + d];
        }
        float v = acc / (1.f + __expf(-acc));   // silu
        xc[idx] = f2bf(v);
    } else {
        int g = blockIdx.x - CONVBLK;
        int b = g / GDIM, j = g % GDIM;
        int tid = threadIdx.x;
        float s = 0.f;
        for (int k = tid; k < DMODEL; k += 256)
            s += xt[b * DMODEL + k] * gw[j * DMODEL + k];
        #pragma unroll
        for (int o = 32; o > 0; o >>= 1) s += __shfl_down(s, o);
        __shared__ float red[4];
        if ((tid & 63) == 0) red[tid >> 6] = s;
        __syncthreads();
        if (tid == 0) {
            float t = red[0] + red[1] + red[2] + red[3] + gb[j];
            gate[b * GDIM + j] = 1.f / (1.f + __expf(-t));
        }
    }
}

// ---------------- reduce 16 split-K partials + gate; split into dt bf16, B, C ----------------
__global__ void gatemul_kernel(const float* __restrict__ xp,   // [16][MROWS][GDIM]
                               const float* __restrict__ gate,
                               ushort_t* __restrict__ dt,
                               float* __restrict__ Bm,
                               float* __restrict__ Cm) {
    int idx = blockIdx.x * 256 + threadIdx.x;
    if (idx >= MROWS * GDIM) return;
    int j  = idx % GDIM;
    int bl = idx / GDIM;
    int b  = bl >> 10;
    float v = 0.f;
    #pragma unroll
    for (int z = 0; z < 16; z++)
        v += xp[(size_t)z * MROWS * GDIM + idx];
    v *= gate[b * GDIM + j];
    if (j < DTRANK)               dt[bl * DTRANK + j] = f2bf(v);
    else if (j < DTRANK + DSTATE) Bm[bl * DSTATE + (j - DTRANK)] = v;
    else                          Cm[bl * DSTATE + (j - DTRANK - DSTATE)] = v;
}

// ---------------- scan pass 1: per-chunk local h and dA-product ----------------
__global__ __launch_bounds__(256)
void scan1_kernel(const ushort_t* __restrict__ delta,
                  const ushort_t* __restrict__ xc,
                  const float* __restrict__ Bm,
                  const float* __restrict__ A_log,
                  float* __restrict__ hfin,
                  float* __restrict__ aprod) {
    __shared__ float sBm[LCHUNK][DSTATE];
    int tid = threadIdx.x;
    int d = blockIdx.x * 256 + tid;
    int b = blockIdx.y;
    int c = blockIdx.z;
    int l0 = c * LCHUNK;
    for (int t = tid; t < LCHUNK * DSTATE; t += 256)
        sBm[t >> 4][t & 15] = Bm[((size_t)(b * SEQLEN + l0 + (t >> 4))) * DSTATE + (t & 15)];
    __syncthreads();

    float Ac[DSTATE];
    #pragma unroll
    for (int n = 0; n < DSTATE; n++)
        Ac[n] = -__expf(A_log[d * DSTATE + n]);
    float h[DSTATE], p[DSTATE];
    #pragma unroll
    for (int n = 0; n < DSTATE; n++) { h[n] = 0.f; p[n] = 1.f; }

    for (int s = 0; s < LCHUNK; s++) {
        size_t ix = (size_t)(b * SEQLEN + l0 + s) * DINNER + d;
        float dv = bf2f(delta[ix]);
        float xv = bf2f(xc[ix]);
        float dx = dv * xv;
        #pragma unroll
        for (int n = 0; n < DSTATE; n++) {
            float e = __expf(dv * Ac[n]);
            h[n] = h[n] * e + dx * sBm[s][n];
            p[n] *= e;
        }
    }
    size_t base = ((size_t)(b * DINNER + d) * NCHUNK + c) * DSTATE;
    #pragma unroll
    for (int n = 0; n < DSTATE; n++) { hfin[base + n] = h[n]; aprod[base + n] = p[n]; }
}

// ---------------- scan pass 3: self-prefix + replay, emit y bf16 in place over xc ----------------
__global__ __launch_bounds__(256)
void scan3_kernel(const ushort_t* __restrict__ delta,
                  ushort_t* __restrict__ xc,     // in: xc, out: y
                  const float* __restrict__ z,
                  const float* __restrict__ Bm,
                  const float* __restrict__ Cm,
                  const float* __restrict__ A_log,
                  const float* __restrict__ Dp,
                  const float* __restrict__ hfin,
                  const float* __restrict__ aprod) {
    __shared__ float sBm[LCHUNK][DSTATE];
    __shared__ float sCm[LCHUNK][DSTATE];
    int tid = threadIdx.x;
    int d = blockIdx.x * 256 + tid;
    int b = blockIdx.y;
    int c = blockIdx.z;
    int l0 = c * LCHUNK;
    for (int t = tid; t < LCHUNK * DSTATE; t += 256) {
        size_t src = ((size_t)(b * SEQLEN + l0 + (t >> 4))) * DSTATE + (t & 15);
        sBm[t >> 4][t & 15] = Bm[src];
        sCm[t >> 4][t & 15] = Cm[src];
    }
    __syncthreads();

    float Ac[DSTATE];
    #pragma unroll
    for (int n = 0; n < DSTATE; n++)
        Ac[n] = -__expf(A_log[d * DSTATE + n]);

    // self-prefix over chunks 0..c-1
    float h[DSTATE];
    #pragma unroll
    for (int n = 0; n < DSTATE; n++) h[n] = 0.f;
    size_t cb = ((size_t)(b * DINNER + d) * NCHUNK) * DSTATE;
    for (int cc = 0; cc < c; cc++) {
        size_t o = cb + (size_t)cc * DSTATE;
        #pragma unroll
        for (int n = 0; n < DSTATE; n++)
            h[n] = hfin[o + n] + aprod[o + n] * h[n];
    }
    float Dv = Dp[d];

    for (int s = 0; s < LCHUNK; s++) {
        size_t ix = (size_t)(b * SEQLEN + l0 + s) * DINNER + d;
        float dv = bf2f(delta[ix]);
        float xv = bf2f(xc[ix]);
        float dx = dv * xv;
        float y = 0.f;
        #pragma unroll
        for (int n = 0; n < DSTATE; n++) {
            float e = __expf(dv * Ac[n]);
            h[n] = h[n] * e + dx * sBm[s][n];
            y += h[n] * sCm[s][n];
        }
        float zv = z[ix];
        float o = (y + Dv * xv) * (zv / (1.f + __expf(-zv)));
        xc[ix] = f2bf(o);                // same thread read-then-write: safe in place
    }
}

// ---------------- out_proj split-K=4 reduce ----------------
__global__ void reduce4_kernel(const float* __restrict__ p, float* __restrict__ out, int n) {
    int i = blockIdx.x * 256 + threadIdx.x;
    if (i < n)
        out[i] = (p[i] + p[(size_t)n + i]) + (p[2 * (size_t)n + i] + p[3 * (size_t)n + i]);
}

// ---------------- launch ----------------
extern "C" void kernel_launch(void* const* d_in, const int* in_sizes, int n_in,
                              void* d_out, int out_size, void* d_ws, size_t ws_size,
                              hipStream_t stream) {
    const float* hidden   = (const float*)d_in[0];
    const float* x_text   = (const float*)d_in[1];
    const float* in_proj  = (const float*)d_in[2];
    const float* conv_w   = (const float*)d_in[3];
    const float* conv_b   = (const float*)d_in[4];
    const float* x_proj   = (const float*)d_in[5];
    const float* dt_proj  = (const float*)d_in[6];
    const float* dt_bias  = (const float*)d_in[7];
    const float* A_log    = (const float*)d_in[8];
    const float* Dparam   = (const float*)d_in[9];
    const float* out_proj = (const float*)d_in[10];
    const float* gate_w   = (const float*)d_in[11];
    const float* gate_b   = (const float*)d_in[12];

    char* ws = (char*)d_ws;
    size_t off = 0;
    auto alloc = [&](size_t bytes) -> char* {
        char* p = ws + off;
        off += (bytes + 255) & ~(size_t)255;
        return p;
    };
    // ~60 MB total. X and zbuf MUST be adjacent (out_proj partials span both).
    ushort_t* hb    = (ushort_t*)alloc((size_t)N1 * 2);   // 4.19 MB
    ushort_t* w_in  = (ushort_t*)alloc((size_t)N2 * 2);   // 8.39 MB -> xc/y after in_proj
    ushort_t* w_x   = (ushort_t*)alloc((size_t)N3 * 2);
    ushort_t* w_dt  = (ushort_t*)alloc((size_t)N4 * 2);
    ushort_t* w_o   = (ushort_t*)alloc((size_t)N5 * 2);   // 4.19 MB
    float*    X     = (float*)alloc((size_t)MROWS * DINNER * 4);  // 16.78 MB (multiple of 256)
    float*    zbuf  = (float*)alloc((size_t)MROWS * DINNER * 4);  // 16.78 MB, adjacent to X
    float*    hfin  = (float*)alloc((size_t)BATCH * DINNER * NCHUNK * DSTATE * 4);  // 4.19 MB
    float*    aprod = (float*)alloc((size_t)BATCH * DINNER * NCHUNK * DSTATE * 4);  // 4.19 MB
    float*    gate  = (float*)alloc((size_t)BATCH * GDIM * 4);
    float*    Bm    = (float*)alloc((size_t)MROWS * DSTATE * 4);
    float*    Cm    = (float*)alloc((size_t)MROWS * DSTATE * 4);
    ushort_t* dt    = (ushort_t*)alloc((size_t)MROWS * DTRANK * 2);

    // aliases (lifetimes disjoint, stream-ordered):
    ushort_t* xc     = w_in;            // xc/y bf16, live after in_proj consumed w_in
    float*    xdbl_p = X;               // 12.6 MB (16 partials), live [x_proj..gatemul]; x dead after conv
    ushort_t* delta  = (ushort_t*)X;    // 8.39 MB bf16, live [dt_proj..scan3]
    float*    outp   = X;               // 33.6 MB (4 partials) spans X+zbuf, live [out_proj..reduce4]

    // 1. convert all GEMM operands to bf16 in one dispatch
    cvt5_kernel<<<(N1 + N2 + N3 + N4 + N5 + 255) / 256, 256, 0, stream>>>(
        hidden, in_proj, x_proj, dt_proj, out_proj, hb, w_in, w_x, w_dt, w_o);

    // 2. in_proj: xz = hidden @ in_proj^T  (2048 x 4096, K=1024) -> x f32 (X) / z f32
    gemm_bf<3><<<dim3(MROWS / 128, (2 * DINNER) / 128, 1), 256, 0, stream>>>(
        hb, w_in, X, zbuf, nullptr, MROWS, 2 * DINNER, DMODEL);

    // 3. conv+silu -> xc bf16 (over dead w_in)  ++  text gate (fused)
    convgate_kernel<<<CONVBLK + BATCH * GDIM, 256, 0, stream>>>(
        X, conv_w, conv_b, xc, x_text, gate_w, gate_b, gate);

    // 4. x_proj: x_dbl = xc @ x_proj^T  (2048 x 96, K=2048), split-K=16 -> partials (X)
    gemm_bf<0><<<dim3(MROWS / 128, 1, 16), 256, 0, stream>>>(
        xc, w_x, xdbl_p, nullptr, nullptr, MROWS, GDIM, DINNER);

    // 5. reduce partials + gate -> dt bf16, Bm, Cm
    gatemul_kernel<<<(MROWS * GDIM + 255) / 256, 256, 0, stream>>>(
        xdbl_p, gate, dt, Bm, Cm);

    // 6. dt_proj + softplus: delta bf16 (2048 x 2048, K=64) -> over dead xdbl_p
    gemm_bf<1><<<dim3(MROWS / 128, DINNER / 128, 1), 256, 0, stream>>>(
        dt, w_dt, delta, nullptr, dt_bias, MROWS, DINNER, DTRANK);

    // 7-8. chunked parallel scan; scan3 self-prefix + replay, y bf16 in place over xc
    scan1_kernel<<<dim3(DINNER / 256, BATCH, NCHUNK), 256, 0, stream>>>(
        delta, xc, Bm, A_log, hfin, aprod);
    scan3_kernel<<<dim3(DINNER / 256, BATCH, NCHUNK), 256, 0, stream>>>(
        delta, xc, zbuf, Bm, Cm, A_log, Dparam, hfin, aprod);

    // 9. out_proj (2048 x 1024, K=2048), split-K=4 -> partials over X+zbuf (both dead)
    gemm_bf<0><<<dim3(MROWS / 128, DMODEL / 128, 4), 256, 0, stream>>>(
        xc, w_o, outp, nullptr, nullptr, MROWS, DMODEL, DINNER);

    // 10. reduce partials -> d_out f32
    reduce4_kernel<<<(MROWS * DMODEL + 255) / 256, 256, 0, stream>>>(
        outp, (float*)d_out, MROWS * DMODEL);
}